// Round 1
// baseline (165.440 us; speedup 1.0000x reference)
//
#include <hip/hip_runtime.h>
#include <hip/hip_bf16.h>

// Problem constants (B, T, C, HS) = (4, 4096, 64, 64)
#define B_ 4
#define T_ 4096

typedef __attribute__((ext_vector_type(8))) short short8;
typedef __attribute__((ext_vector_type(4))) float f32x4;
typedef unsigned short ushort_t;
typedef unsigned int uint32;

__device__ __forceinline__ ushort_t bf16_of(float f) {
    __hip_bfloat16 h = __float2bfloat16(f);
    return __builtin_bit_cast(unsigned short, h);
}

// ---------------------------------------------------------------------------
// Kernel 1: QKV projection (fp32 accurate), writes split-bf16 Q/K, bf16 V^T.
// Q is pre-scaled by sqrt(C)*log2(e) so attention uses exp2 directly.
// grid = B*T/16 = 1024 blocks, 192 threads (wave 0 -> Q, 1 -> K, 2 -> V).
// ---------------------------------------------------------------------------
__global__ __launch_bounds__(192) void qkv_proj(
    const float* __restrict__ x, const float* __restrict__ Wq,
    const float* __restrict__ Wk, const float* __restrict__ Wv,
    ushort_t* __restrict__ Qhi, ushort_t* __restrict__ Qlo,
    ushort_t* __restrict__ Khi, ushort_t* __restrict__ Klo,
    ushort_t* __restrict__ Vt)
{
    const int t = threadIdx.x;
    const int role = t >> 6;   // 0=Q 1=K 2=V
    const int col = t & 63;
    const int r0 = blockIdx.x * 16;   // global row base in [0, B*T)

    const float* W = (role == 0) ? Wq : (role == 1) ? Wk : Wv;
    float wc[64];
#pragma unroll
    for (int c = 0; c < 64; ++c) wc[c] = W[c * 64 + col];

    const float QS = 11.541560327111707f;  // 8 * log2(e)
    uint32 vp[8];

#pragma unroll
    for (int r = 0; r < 16; ++r) {
        const float* xr = x + (size_t)(r0 + r) * 64;
        float acc = 0.f;
#pragma unroll
        for (int c = 0; c < 64; c += 4) {
            float4 xv = *(const float4*)(xr + c);
            acc += xv.x * wc[c] + xv.y * wc[c + 1] + xv.z * wc[c + 2] + xv.w * wc[c + 3];
        }
        if (role == 0) {
            float v = acc * QS;
            __hip_bfloat16 h = __float2bfloat16(v);
            float fh = __bfloat162float(h);
            Qhi[(size_t)(r0 + r) * 64 + col] = __builtin_bit_cast(unsigned short, h);
            Qlo[(size_t)(r0 + r) * 64 + col] = bf16_of(v - fh);
        } else if (role == 1) {
            __hip_bfloat16 h = __float2bfloat16(acc);
            float fh = __bfloat162float(h);
            Khi[(size_t)(r0 + r) * 64 + col] = __builtin_bit_cast(unsigned short, h);
            Klo[(size_t)(r0 + r) * 64 + col] = bf16_of(acc - fh);
        } else {
            ushort_t u = bf16_of(acc);
            if (r & 1) vp[r >> 1] |= ((uint32)u) << 16; else vp[r >> 1] = (uint32)u;
        }
    }
    if (role == 2) {
        const int b = r0 >> 12;
        const int tr = r0 & (T_ - 1);
        uint32* dst = (uint32*)(Vt + ((size_t)(b * 64 + col)) * T_ + tr);
#pragma unroll
        for (int i = 0; i < 8; ++i) dst[i] = vp[i];
    }
}

// ---------------------------------------------------------------------------
// Kernel 2: causal flash attention, split-bf16 MFMA QK^T + bf16 PV.
// Block: 256 threads = 4 waves. Wave w: q-subtile s = w&1 (16 rows),
// k-parity p = w>>1 (processes k-tiles p, p+2, ...). 32 q-rows per block.
// grid = B * (T/32) = 512, q-tiles ordered big-then-small for balance.
// ---------------------------------------------------------------------------
__global__ __launch_bounds__(256) void flash_attn(
    const ushort_t* __restrict__ Qhi, const ushort_t* __restrict__ Qlo,
    const ushort_t* __restrict__ Khi, const ushort_t* __restrict__ Klo,
    const ushort_t* __restrict__ Vt, float* __restrict__ out)
{
    // rows padded to 80 bf16 (160B, 16B aligned) -> near-conflict-free b128
    __shared__ ushort_t Kh[2][64][80];
    __shared__ ushort_t Kl[2][64][80];
    __shared__ ushort_t Vs[2][64][80];
    __shared__ ushort_t Pb[4][16][80];

    const int tid = threadIdx.x;
    const int w = tid >> 6;
    const int lane = tid & 63;
    const int s = w & 1;
    const int p = w >> 1;
    const int l16 = lane & 15;
    const int g = lane >> 4;

    const int bid = blockIdx.x;
    const int b = bid & 3;
    const int jd = bid >> 2;
    const int i = (jd < 64) ? (127 - jd) : (jd - 64);  // big tiles dispatched first
    const int q0 = i * 32;                             // within-batch row base
    const int nkt = (q0 + 32 + 63) >> 6;               // # of 64-wide k-tiles
    const int J = (nkt + 1) >> 1;

    // Q A-fragments (held in regs for the whole kernel).
    // A layout: row = lane&15, k = 8*(lane>>4)+j (contiguous 8 along K).
    const int qrow = q0 + s * 16 + l16;
    const size_t qbase = ((size_t)(b * T_ + qrow)) * 64;
    short8 aQh[2], aQl[2];
#pragma unroll
    for (int cc = 0; cc < 2; ++cc) {
        aQh[cc] = *(const short8*)(Qhi + qbase + cc * 32 + g * 8);
        aQl[cc] = *(const short8*)(Qlo + qbase + cc * 32 + g * 8);
    }

    float m[4], lsum[4];
    f32x4 acc[4];
#pragma unroll
    for (int r = 0; r < 4; ++r) { m[r] = -__builtin_inff(); lsum[r] = 0.f; }
#pragma unroll
    for (int hs = 0; hs < 4; ++hs) acc[hs] = (f32x4){0.f, 0.f, 0.f, 0.f};

    for (int j = 0; j < J; ++j) {
        // ---- cooperative staging of both parity tiles ----
        const int rstage = tid >> 2;           // 0..63 (key row / h row)
        const int cstage = (tid & 3) * 16;
#pragma unroll
        for (int pi = 0; pi < 2; ++pi) {
            const int kt = 2 * j + pi;
            if (kt < nkt) {
                const size_t gk = ((size_t)(b * T_ + kt * 64 + rstage)) * 64 + cstage;
                const size_t gv = ((size_t)(b * 64 + rstage)) * T_ + kt * 64 + cstage;
#pragma unroll
                for (int u = 0; u < 2; ++u) {
                    *(short8*)&Kh[pi][rstage][cstage + 8 * u] = *(const short8*)(Khi + gk + 8 * u);
                    *(short8*)&Kl[pi][rstage][cstage + 8 * u] = *(const short8*)(Klo + gk + 8 * u);
                    *(short8*)&Vs[pi][rstage][cstage + 8 * u] = *(const short8*)(Vt + gv + 8 * u);
                }
            }
        }
        __syncthreads();

        const int kt = 2 * j + p;
        if (kt < nkt) {
            // ---- scores: S = Q·K^T (split bf16: hi*hi + hi*lo + lo*hi) ----
            f32x4 sc[4];
#pragma unroll
            for (int ks = 0; ks < 4; ++ks) {
                f32x4 a = (f32x4){0.f, 0.f, 0.f, 0.f};
#pragma unroll
                for (int cc = 0; cc < 2; ++cc) {
                    short8 bh = *(const short8*)&Kh[p][ks * 16 + l16][cc * 32 + 8 * g];
                    short8 bl = *(const short8*)&Kl[p][ks * 16 + l16][cc * 32 + 8 * g];
                    a = __builtin_amdgcn_mfma_f32_16x16x32_bf16(aQh[cc], bh, a, 0, 0, 0);
                    a = __builtin_amdgcn_mfma_f32_16x16x32_bf16(aQh[cc], bl, a, 0, 0, 0);
                    a = __builtin_amdgcn_mfma_f32_16x16x32_bf16(aQl[cc], bh, a, 0, 0, 0);
                }
                sc[ks] = a;
            }
            // ---- causal mask (only the diagonal tile can cross) ----
            if (kt == nkt - 1) {
#pragma unroll
                for (int ks = 0; ks < 4; ++ks)
#pragma unroll
                    for (int r = 0; r < 4; ++r) {
                        int key = kt * 64 + ks * 16 + l16;
                        int row = q0 + s * 16 + 4 * g + r;
                        if (key > row) sc[ks][r] = -__builtin_inff();
                    }
            }
            // ---- online softmax (exp2 domain; scale folded into Q) ----
            float al[4];
#pragma unroll
            for (int r = 0; r < 4; ++r) {
                float mt = fmaxf(fmaxf(sc[0][r], sc[1][r]), fmaxf(sc[2][r], sc[3][r]));
#pragma unroll
                for (int msk = 1; msk < 16; msk <<= 1) mt = fmaxf(mt, __shfl_xor(mt, msk));
                float mn = fmaxf(m[r], mt);
                al[r] = exp2f(m[r] - mn);   // exp2f(-inf) == 0 on first tile
                m[r] = mn;
            }
            float rs[4] = {0.f, 0.f, 0.f, 0.f};
#pragma unroll
            for (int ks = 0; ks < 4; ++ks) {
#pragma unroll
                for (int r = 0; r < 4; ++r) {
                    float pv = exp2f(sc[ks][r] - m[r]);
                    rs[r] += pv;
                    Pb[w][4 * g + r][ks * 16 + l16] = bf16_of(pv);
                }
            }
#pragma unroll
            for (int r = 0; r < 4; ++r) {
#pragma unroll
                for (int msk = 1; msk < 16; msk <<= 1) rs[r] += __shfl_xor(rs[r], msk);
                lsum[r] = lsum[r] * al[r] + rs[r];
            }
#pragma unroll
            for (int hs = 0; hs < 4; ++hs)
#pragma unroll
                for (int r = 0; r < 4; ++r) acc[hs][r] *= al[r];
            // ---- PV: acc += P · V  (P round-trips through per-wave LDS) ----
#pragma unroll
            for (int cc = 0; cc < 2; ++cc) {
                short8 ap = *(const short8*)&Pb[w][l16][cc * 32 + 8 * g];
#pragma unroll
                for (int hs = 0; hs < 4; ++hs) {
                    short8 bv = *(const short8*)&Vs[p][hs * 16 + l16][cc * 32 + 8 * g];
                    acc[hs] = __builtin_amdgcn_mfma_f32_16x16x32_bf16(ap, bv, acc[hs], 0, 0, 0);
                }
            }
        }
        __syncthreads();
    }

    // ---- merge the two k-parity partials, normalize, write out ----
    float* mb = (float*)&Kh[0][0][0];          // reuse LDS: 2*64*24*4B = 12KB
    float* mine = mb + (size_t)(s * 64 + lane) * 24;
    if (p == 1) {
#pragma unroll
        for (int r = 0; r < 4; ++r) { mine[r] = m[r]; mine[4 + r] = lsum[r]; }
#pragma unroll
        for (int hs = 0; hs < 4; ++hs)
#pragma unroll
            for (int r = 0; r < 4; ++r) mine[8 + hs * 4 + r] = acc[hs][r];
    }
    __syncthreads();
    if (p == 0) {
#pragma unroll
        for (int r = 0; r < 4; ++r) {
            float m1 = mine[r], l1 = mine[4 + r];
            float mf = fmaxf(m[r], m1);
            float a0 = exp2f(m[r] - mf);
            float a1 = exp2f(m1 - mf);     // m1 == -inf (no tiles) -> 0
            float lf = lsum[r] * a0 + l1 * a1;
            float inv = 1.f / lf;
#pragma unroll
            for (int hs = 0; hs < 4; ++hs) {
                float of = (acc[hs][r] * a0 + mine[8 + hs * 4 + r] * a1) * inv;
                out[((size_t)(b * T_ + q0 + s * 16 + 4 * g + r)) * 64 + hs * 16 + l16] = of;
            }
        }
    }
}

// ---------------------------------------------------------------------------
extern "C" void kernel_launch(void* const* d_in, const int* in_sizes, int n_in,
                              void* d_out, int out_size, void* d_ws, size_t ws_size,
                              hipStream_t stream) {
    const float* x  = (const float*)d_in[0];
    const float* Wq = (const float*)d_in[1];
    const float* Wk = (const float*)d_in[2];
    const float* Wv = (const float*)d_in[3];
    float* out = (float*)d_out;

    // workspace carve: 5 arrays of B*T*64 bf16 (2MB each, 10MB total)
    const size_t N = (size_t)B_ * T_ * 64;
    ushort_t* Qhi = (ushort_t*)d_ws;
    ushort_t* Qlo = Qhi + N;
    ushort_t* Khi = Qlo + N;
    ushort_t* Klo = Khi + N;
    ushort_t* Vt  = Klo + N;

    qkv_proj<<<(B_ * T_) / 16, 192, 0, stream>>>(x, Wq, Wk, Wv, Qhi, Qlo, Khi, Klo, Vt);
    flash_attn<<<B_ * (T_ / 32), 256, 0, stream>>>(Qhi, Qlo, Khi, Klo, Vt, out);
}

// Round 2
// 158.043 us; speedup vs baseline: 1.0468x; 1.0468x over previous
//
#include <hip/hip_runtime.h>
#include <hip/hip_bf16.h>

// Problem constants (B, T, C, HS) = (4, 4096, 64, 64)
#define B_ 4
#define T_ 4096

typedef __attribute__((ext_vector_type(8))) short short8;
typedef __attribute__((ext_vector_type(4))) float f32x4;
typedef unsigned short ushort_t;
typedef unsigned int uint32;

__device__ __forceinline__ ushort_t bf16_of(float f) {
    __hip_bfloat16 h = __float2bfloat16(f);
    return __builtin_bit_cast(unsigned short, h);
}

// ---------------------------------------------------------------------------
// Kernel 1: QKV projection via MFMA (split-bf16 x and W, fp32 accumulate).
// Writes split-bf16 Q (pre-scaled by sqrt(C)*log2e) and K, bf16 V^T.
// grid = 512 blocks x 256 thr. Block owns 32 rows; wave w: row-tile (w&1),
// unit-half (w>>1) over 12 units = 3 matrices x 4 col-tiles.
// ---------------------------------------------------------------------------
__global__ __launch_bounds__(256) void qkv_proj(
    const float* __restrict__ x, const float* __restrict__ Wq,
    const float* __restrict__ Wk, const float* __restrict__ Wv,
    ushort_t* __restrict__ Qhi, ushort_t* __restrict__ Qlo,
    ushort_t* __restrict__ Khi, ushort_t* __restrict__ Klo,
    ushort_t* __restrict__ Vt)
{
    __shared__ float Ws[3][64][65];   // pad 65: 2-way (free) bank pattern
    const int tid = threadIdx.x;
    {
        const float* Wp[3] = {Wq, Wk, Wv};
        for (int mm = 0; mm < 3; ++mm)
            for (int ii = tid; ii < 4096; ii += 256)
                Ws[mm][ii >> 6][ii & 63] = Wp[mm][ii];
    }
    __syncthreads();

    const int w = tid >> 6, lane = tid & 63;
    const int l16 = lane & 15, g = lane >> 4;
    const int R0 = blockIdx.x * 32 + 16 * (w & 1);
    const int h = w >> 1;

    // A-fragments from x rows (row = l16, k = cc*32 + 8g + j), split bf16
    short8 ah[2], al[2];
#pragma unroll
    for (int cc = 0; cc < 2; ++cc) {
        const float* xp = x + (size_t)(R0 + l16) * 64 + cc * 32 + 8 * g;
        float4 v0 = *(const float4*)xp;
        float4 v1 = *(const float4*)(xp + 4);
        float xv[8] = {v0.x, v0.y, v0.z, v0.w, v1.x, v1.y, v1.z, v1.w};
#pragma unroll
        for (int jj = 0; jj < 8; ++jj) {
            __hip_bfloat16 hh = __float2bfloat16(xv[jj]);
            ah[cc][jj] = (short)__builtin_bit_cast(unsigned short, hh);
            al[cc][jj] = (short)bf16_of(xv[jj] - __bfloat162float(hh));
        }
    }

    const float QS = 11.541560327111707f;  // sqrt(64) * log2(e)
#pragma unroll
    for (int u6 = 0; u6 < 6; ++u6) {
        const int u = h * 6 + u6;
        const int mm = u >> 2, ct = u & 3;     // matrix, col-tile
        f32x4 d = (f32x4){0.f, 0.f, 0.f, 0.f};
#pragma unroll
        for (int cc = 0; cc < 2; ++cc) {
            // B-fragment: B[n=ct*16+l16][k=cc*32+8g+j] = W[k][n], split bf16
            short8 bh, bl;
#pragma unroll
            for (int jj = 0; jj < 8; ++jj) {
                float wv = Ws[mm][cc * 32 + 8 * g + jj][ct * 16 + l16];
                __hip_bfloat16 hh = __float2bfloat16(wv);
                bh[jj] = (short)__builtin_bit_cast(unsigned short, hh);
                bl[jj] = (short)bf16_of(wv - __bfloat162float(hh));
            }
            d = __builtin_amdgcn_mfma_f32_16x16x32_bf16(ah[cc], bh, d, 0, 0, 0);
            d = __builtin_amdgcn_mfma_f32_16x16x32_bf16(ah[cc], bl, d, 0, 0, 0);
            d = __builtin_amdgcn_mfma_f32_16x16x32_bf16(al[cc], bh, d, 0, 0, 0);
        }
        // C/D layout: col = l16, row = 4g + reg (m89-verified)
        const int col = ct * 16 + l16;
        if (mm == 0) {
#pragma unroll
            for (int r = 0; r < 4; ++r) {
                const int R = R0 + 4 * g + r;
                float v = d[r] * QS;
                __hip_bfloat16 hh = __float2bfloat16(v);
                Qhi[(size_t)R * 64 + col] = __builtin_bit_cast(unsigned short, hh);
                Qlo[(size_t)R * 64 + col] = bf16_of(v - __bfloat162float(hh));
            }
        } else if (mm == 1) {
#pragma unroll
            for (int r = 0; r < 4; ++r) {
                const int R = R0 + 4 * g + r;
                float v = d[r];
                __hip_bfloat16 hh = __float2bfloat16(v);
                Khi[(size_t)R * 64 + col] = __builtin_bit_cast(unsigned short, hh);
                Klo[(size_t)R * 64 + col] = bf16_of(v - __bfloat162float(hh));
            }
        } else {
            // V^T [b][64][T]: rows 4g+r are consecutive t -> one 8B store
            const int bb = R0 >> 12;
            const int t0 = (R0 & (T_ - 1)) + 4 * g;
            uint32 lo = (uint32)bf16_of(d[0]) | ((uint32)bf16_of(d[1]) << 16);
            uint32 hi = (uint32)bf16_of(d[2]) | ((uint32)bf16_of(d[3]) << 16);
            uint2 pk; pk.x = lo; pk.y = hi;
            *(uint2*)(Vt + ((size_t)(bb * 64 + col)) * T_ + t0) = pk;
        }
    }
}

// ---------------------------------------------------------------------------
// Kernel 2: causal flash attention. No K/V LDS staging (K/V are L2-resident;
// XCD-aware mapping keeps each batch's 3MB K/V on 2 XCDs). 4 waves = 4-way
// key parity; each wave owns all 32 q-rows (2 subtiles) -> every K/V
// fragment load feeds 2x MFMAs. Barrier-free main loop; one merge sync.
// grid = 512 (B * T/32), big q-tiles first per XCD.
// ---------------------------------------------------------------------------
__global__ __launch_bounds__(256, 2) void flash_attn(
    const ushort_t* __restrict__ Qhi, const ushort_t* __restrict__ Qlo,
    const ushort_t* __restrict__ Khi, const ushort_t* __restrict__ Klo,
    const ushort_t* __restrict__ Vt, float* __restrict__ out)
{
    __shared__ __align__(16) ushort_t Pb[4][2][16][72];  // per-wave P buffer
    __shared__ float mrg[2][64][3][26];                  // parity-merge buffer

    const int tid = threadIdx.x;
    const int p = tid >> 6;                 // wave index = key parity 0..3
    const int lane = tid & 63;
    const int l16 = lane & 15, g = lane >> 4;

    // XCD-aware mapping: xcd = bid&7 -> batch (xcd&3); big tiles first,
    // odd/even i interleaved across the two XCDs of a batch (balance).
    const int bid = blockIdx.x;
    const int xg = bid & 7;
    const int b = xg & 3;
    const int jj = bid >> 3;                             // 0..63
    const int i = (xg >> 2) ? (126 - 2 * jj) : (127 - 2 * jj);
    const int q0 = i * 32;
    const int nkt = (q0 + 32 + 63) >> 6;

    // Q fragments for both 16-row subtiles (A: row=l16, k=cc*32+8g+j)
    short8 aQh[2][2], aQl[2][2];
#pragma unroll
    for (int su = 0; su < 2; ++su) {
        const size_t qb = ((size_t)(b * T_ + q0 + su * 16 + l16)) * 64;
#pragma unroll
        for (int cc = 0; cc < 2; ++cc) {
            aQh[su][cc] = *(const short8*)(Qhi + qb + cc * 32 + 8 * g);
            aQl[su][cc] = *(const short8*)(Qlo + qb + cc * 32 + 8 * g);
        }
    }

    float m[2][4], lsum[2][4];
    f32x4 acc[2][4];
#pragma unroll
    for (int su = 0; su < 2; ++su)
#pragma unroll
        for (int r = 0; r < 4; ++r) { m[su][r] = -__builtin_inff(); lsum[su][r] = 0.f; }
#pragma unroll
    for (int su = 0; su < 2; ++su)
#pragma unroll
        for (int hs = 0; hs < 4; ++hs) acc[su][hs] = (f32x4){0.f, 0.f, 0.f, 0.f};

    for (int kt = p; kt < nkt; kt += 4) {
        const size_t kb = ((size_t)(b * T_ + kt * 64)) * 64;
        f32x4 sc[2][4];
        // ---- QK^T (split bf16: hi*hi + hi*lo + lo*hi), direct from L2 ----
        __builtin_amdgcn_s_setprio(1);
#pragma unroll
        for (int ks = 0; ks < 4; ++ks) {
            f32x4 a0 = (f32x4){0.f, 0.f, 0.f, 0.f};
            f32x4 a1 = (f32x4){0.f, 0.f, 0.f, 0.f};
#pragma unroll
            for (int cc = 0; cc < 2; ++cc) {
                const size_t ko = kb + ((size_t)(ks * 16 + l16)) * 64 + cc * 32 + 8 * g;
                short8 bh = *(const short8*)(Khi + ko);
                short8 bl = *(const short8*)(Klo + ko);
                a0 = __builtin_amdgcn_mfma_f32_16x16x32_bf16(aQh[0][cc], bh, a0, 0, 0, 0);
                a0 = __builtin_amdgcn_mfma_f32_16x16x32_bf16(aQh[0][cc], bl, a0, 0, 0, 0);
                a0 = __builtin_amdgcn_mfma_f32_16x16x32_bf16(aQl[0][cc], bh, a0, 0, 0, 0);
                a1 = __builtin_amdgcn_mfma_f32_16x16x32_bf16(aQh[1][cc], bh, a1, 0, 0, 0);
                a1 = __builtin_amdgcn_mfma_f32_16x16x32_bf16(aQh[1][cc], bl, a1, 0, 0, 0);
                a1 = __builtin_amdgcn_mfma_f32_16x16x32_bf16(aQl[1][cc], bh, a1, 0, 0, 0);
            }
            sc[0][ks] = a0; sc[1][ks] = a1;
        }
        __builtin_amdgcn_s_setprio(0);
        // ---- causal mask (only diagonal tile crosses) ----
        if (kt == nkt - 1) {
#pragma unroll
            for (int su = 0; su < 2; ++su)
#pragma unroll
                for (int ks = 0; ks < 4; ++ks)
#pragma unroll
                    for (int r = 0; r < 4; ++r) {
                        int key = kt * 64 + ks * 16 + l16;
                        int row = q0 + su * 16 + 4 * g + r;
                        if (key > row) sc[su][ks][r] = -__builtin_inff();
                    }
        }
        // ---- online softmax (exp2 domain) + P to LDS, per subtile ----
        float alv[2][4];
#pragma unroll
        for (int su = 0; su < 2; ++su) {
#pragma unroll
            for (int r = 0; r < 4; ++r) {
                float mt = fmaxf(fmaxf(sc[su][0][r], sc[su][1][r]),
                                 fmaxf(sc[su][2][r], sc[su][3][r]));
#pragma unroll
                for (int msk = 1; msk < 16; msk <<= 1) mt = fmaxf(mt, __shfl_xor(mt, msk));
                float mn = fmaxf(m[su][r], mt);
                alv[su][r] = exp2f(m[su][r] - mn);   // exp2f(-inf) == 0 first tile
                m[su][r] = mn;
            }
            float rs[4] = {0.f, 0.f, 0.f, 0.f};
#pragma unroll
            for (int ks = 0; ks < 4; ++ks)
#pragma unroll
                for (int r = 0; r < 4; ++r) {
                    float pv = exp2f(sc[su][ks][r] - m[su][r]);
                    rs[r] += pv;
                    Pb[p][su][4 * g + r][ks * 16 + l16] = bf16_of(pv);
                }
#pragma unroll
            for (int r = 0; r < 4; ++r) {
#pragma unroll
                for (int msk = 1; msk < 16; msk <<= 1) rs[r] += __shfl_xor(rs[r], msk);
                lsum[su][r] = lsum[su][r] * alv[su][r] + rs[r];
            }
#pragma unroll
            for (int hs = 0; hs < 4; ++hs)
#pragma unroll
                for (int r = 0; r < 4; ++r) acc[su][hs][r] *= alv[su][r];
        }
        // ---- PV: shared V fragment feeds both subtiles ----
        __builtin_amdgcn_s_setprio(1);
#pragma unroll
        for (int cc = 0; cc < 2; ++cc) {
            short8 ap0 = *(const short8*)&Pb[p][0][l16][cc * 32 + 8 * g];
            short8 ap1 = *(const short8*)&Pb[p][1][l16][cc * 32 + 8 * g];
#pragma unroll
            for (int hs = 0; hs < 4; ++hs) {
                short8 bv = *(const short8*)(Vt + ((size_t)(b * 64 + hs * 16 + l16)) * T_
                                             + kt * 64 + cc * 32 + 8 * g);
                acc[0][hs] = __builtin_amdgcn_mfma_f32_16x16x32_bf16(ap0, bv, acc[0][hs], 0, 0, 0);
                acc[1][hs] = __builtin_amdgcn_mfma_f32_16x16x32_bf16(ap1, bv, acc[1][hs], 0, 0, 0);
            }
        }
        __builtin_amdgcn_s_setprio(0);
    }

    // ---- 4-way parity merge ----
    if (p > 0) {
#pragma unroll
        for (int su = 0; su < 2; ++su) {
            float* mp = &mrg[su][lane][p - 1][0];
#pragma unroll
            for (int r = 0; r < 4; ++r) { mp[r] = m[su][r]; mp[4 + r] = lsum[su][r]; }
#pragma unroll
            for (int hs = 0; hs < 4; ++hs)
#pragma unroll
                for (int r = 0; r < 4; ++r) mp[8 + hs * 4 + r] = acc[su][hs][r];
        }
    }
    __syncthreads();
    if (p == 0) {
#pragma unroll
        for (int su = 0; su < 2; ++su) {
#pragma unroll
            for (int r = 0; r < 4; ++r) {
                float mm = m[su][r], ll = lsum[su][r];
                float ac[4];
#pragma unroll
                for (int hs = 0; hs < 4; ++hs) ac[hs] = acc[su][hs][r];
#pragma unroll
                for (int pp = 0; pp < 3; ++pp) {
                    const float* mp = &mrg[su][lane][pp][0];
                    float m1 = mp[r], l1 = mp[4 + r];
                    float mf = fmaxf(mm, m1);
                    float a0 = exp2f(mm - mf);
                    float a1 = exp2f(m1 - mf);     // m1 == -inf (empty) -> 0
                    ll = ll * a0 + l1 * a1;
#pragma unroll
                    for (int hs = 0; hs < 4; ++hs)
                        ac[hs] = ac[hs] * a0 + mp[8 + hs * 4 + r] * a1;
                    mm = mf;
                }
                float inv = 1.f / ll;
                const size_t ob = ((size_t)(b * T_ + q0 + su * 16 + 4 * g + r)) * 64;
#pragma unroll
                for (int hs = 0; hs < 4; ++hs) out[ob + hs * 16 + l16] = ac[hs] * inv;
            }
        }
    }
}

// ---------------------------------------------------------------------------
extern "C" void kernel_launch(void* const* d_in, const int* in_sizes, int n_in,
                              void* d_out, int out_size, void* d_ws, size_t ws_size,
                              hipStream_t stream) {
    const float* x  = (const float*)d_in[0];
    const float* Wq = (const float*)d_in[1];
    const float* Wk = (const float*)d_in[2];
    const float* Wv = (const float*)d_in[3];
    float* out = (float*)d_out;

    // workspace carve: 5 arrays of B*T*64 bf16 (2MB each, 10MB total)
    const size_t N = (size_t)B_ * T_ * 64;
    ushort_t* Qhi = (ushort_t*)d_ws;
    ushort_t* Qlo = Qhi + N;
    ushort_t* Khi = Qlo + N;
    ushort_t* Klo = Khi + N;
    ushort_t* Vt  = Klo + N;

    qkv_proj<<<512, 256, 0, stream>>>(x, Wq, Wk, Wv, Qhi, Qlo, Khi, Klo, Vt);
    flash_attn<<<512, 256, 0, stream>>>(Qhi, Qlo, Khi, Klo, Vt, out);
}

// Round 4
// 149.912 us; speedup vs baseline: 1.1036x; 1.0542x over previous
//
#include <hip/hip_runtime.h>
#include <hip/hip_bf16.h>

// Problem constants (B, T, C, HS) = (4, 4096, 64, 64)
#define B_ 4
#define T_ 4096
#define UPB 4160      // units per batch: sum_i nkt_i, nkt_i = i/2+1, i<128

typedef __attribute__((ext_vector_type(8))) short short8;
typedef __attribute__((ext_vector_type(4))) float f32x4;
typedef unsigned short ushort_t;
typedef unsigned int uint32;

__device__ __forceinline__ ushort_t bf16_of(float f) {
    __hip_bfloat16 h = __float2bfloat16(f);
    return __builtin_bit_cast(unsigned short, h);
}
__device__ __forceinline__ float f_of_bf16(ushort_t u) {
    uint32 x = ((uint32)u) << 16;
    return __builtin_bit_cast(float, x);
}

// ---------------------------------------------------------------------------
// Kernel 1: QKV projection via MFMA (verbatim from round 2 — passed).
// ---------------------------------------------------------------------------
__global__ __launch_bounds__(256) void qkv_proj(
    const float* __restrict__ x, const float* __restrict__ Wq,
    const float* __restrict__ Wk, const float* __restrict__ Wv,
    ushort_t* __restrict__ Qhi, ushort_t* __restrict__ Qlo,
    ushort_t* __restrict__ Khi, ushort_t* __restrict__ Klo,
    ushort_t* __restrict__ Vt)
{
    __shared__ float Ws[3][64][65];
    const int tid = threadIdx.x;
    {
        const float* Wp[3] = {Wq, Wk, Wv};
        for (int mm = 0; mm < 3; ++mm)
            for (int ii = tid; ii < 4096; ii += 256)
                Ws[mm][ii >> 6][ii & 63] = Wp[mm][ii];
    }
    __syncthreads();

    const int w = tid >> 6, lane = tid & 63;
    const int l16 = lane & 15, g = lane >> 4;
    const int R0 = blockIdx.x * 32 + 16 * (w & 1);
    const int h = w >> 1;

    short8 ah[2], al[2];
#pragma unroll
    for (int cc = 0; cc < 2; ++cc) {
        const float* xp = x + (size_t)(R0 + l16) * 64 + cc * 32 + 8 * g;
        float4 v0 = *(const float4*)xp;
        float4 v1 = *(const float4*)(xp + 4);
        float xv[8] = {v0.x, v0.y, v0.z, v0.w, v1.x, v1.y, v1.z, v1.w};
#pragma unroll
        for (int jj = 0; jj < 8; ++jj) {
            __hip_bfloat16 hh = __float2bfloat16(xv[jj]);
            ah[cc][jj] = (short)__builtin_bit_cast(unsigned short, hh);
            al[cc][jj] = (short)bf16_of(xv[jj] - __bfloat162float(hh));
        }
    }

    const float QS = 11.541560327111707f;  // sqrt(64) * log2(e)
#pragma unroll
    for (int u6 = 0; u6 < 6; ++u6) {
        const int u = h * 6 + u6;
        const int mm = u >> 2, ct = u & 3;
        f32x4 d = (f32x4){0.f, 0.f, 0.f, 0.f};
#pragma unroll
        for (int cc = 0; cc < 2; ++cc) {
            short8 bh, bl;
#pragma unroll
            for (int jj = 0; jj < 8; ++jj) {
                float wv = Ws[mm][cc * 32 + 8 * g + jj][ct * 16 + l16];
                __hip_bfloat16 hh = __float2bfloat16(wv);
                bh[jj] = (short)__builtin_bit_cast(unsigned short, hh);
                bl[jj] = (short)bf16_of(wv - __bfloat162float(hh));
            }
            d = __builtin_amdgcn_mfma_f32_16x16x32_bf16(ah[cc], bh, d, 0, 0, 0);
            d = __builtin_amdgcn_mfma_f32_16x16x32_bf16(ah[cc], bl, d, 0, 0, 0);
            d = __builtin_amdgcn_mfma_f32_16x16x32_bf16(al[cc], bh, d, 0, 0, 0);
        }
        const int col = ct * 16 + l16;
        if (mm == 0) {
#pragma unroll
            for (int r = 0; r < 4; ++r) {
                const int R = R0 + 4 * g + r;
                float v = d[r] * QS;
                __hip_bfloat16 hh = __float2bfloat16(v);
                Qhi[(size_t)R * 64 + col] = __builtin_bit_cast(unsigned short, hh);
                Qlo[(size_t)R * 64 + col] = bf16_of(v - __bfloat162float(hh));
            }
        } else if (mm == 1) {
#pragma unroll
            for (int r = 0; r < 4; ++r) {
                const int R = R0 + 4 * g + r;
                float v = d[r];
                __hip_bfloat16 hh = __float2bfloat16(v);
                Khi[(size_t)R * 64 + col] = __builtin_bit_cast(unsigned short, hh);
                Klo[(size_t)R * 64 + col] = bf16_of(v - __bfloat162float(hh));
            }
        } else {
            const int bb = R0 >> 12;
            const int t0 = (R0 & (T_ - 1)) + 4 * g;
            uint32 lo = (uint32)bf16_of(d[0]) | ((uint32)bf16_of(d[1]) << 16);
            uint32 hi = (uint32)bf16_of(d[2]) | ((uint32)bf16_of(d[3]) << 16);
            uint2 pk; pk.x = lo; pk.y = hi;
            *(uint2*)(Vt + ((size_t)(bb * 64 + col)) * T_ + t0) = pk;
        }
    }
}

// ---------------------------------------------------------------------------
// Kernel 2: stream-K flash attention. Units = flattened (q-tile, k-tile)
// pairs; wave W owns units [65W/S, 65(W+1)/S) (S = nwaves/256) — exactly
// balanced. Partials (m,l fp32; acc bf16) flushed at tile boundaries.
// ---------------------------------------------------------------------------
__global__ __launch_bounds__(256, 3) void flash_sk(
    const ushort_t* __restrict__ Qhi, const ushort_t* __restrict__ Qlo,
    const ushort_t* __restrict__ Khi, const ushort_t* __restrict__ Klo,
    const ushort_t* __restrict__ Vt,
    ushort_t* __restrict__ PACC, float* __restrict__ PML,
    const int S, const int SLOTS)
{
    __shared__ __align__(16) ushort_t Pb[4][2][16][72];

    const int tid = threadIdx.x;
    const int wv = tid >> 6;
    const int lane = tid & 63;
    const int l16 = lane & 15, g = lane >> 4;

    const int W = blockIdx.x * 4 + wv;
    int u = (65 * W) / S;
    const int uEnd = (65 * (W + 1)) / S;

    while (u < uEnd) {
        const int b = u / UPB;
        const int r = u - b * UPB;
        int t = (int)sqrtf((float)r);
        while ((t + 1) * (t + 1) <= r) ++t;
        while (t * t > r) --t;
        int i, kt0;
        if (r < t * t + t) { i = 2 * t - 1; kt0 = r - t * t; }
        else               { i = 2 * t;     kt0 = r - t * t - t; }
        const int nkt = (i >> 1) + 1;
        const int q0 = i * 32;
        const int rem = nkt - kt0;
        const int avail = uEnd - u;
        const int run = (rem < avail) ? rem : avail;

        // Q fragments for both 16-row subtiles (A: row=l16, k=cc*32+8g+j)
        short8 aQh[2][2], aQl[2][2];
#pragma unroll
        for (int su = 0; su < 2; ++su) {
            const size_t qb = ((size_t)(b * T_ + q0 + su * 16 + l16)) * 64;
#pragma unroll
            for (int cc = 0; cc < 2; ++cc) {
                aQh[su][cc] = *(const short8*)(Qhi + qb + cc * 32 + 8 * g);
                aQl[su][cc] = *(const short8*)(Qlo + qb + cc * 32 + 8 * g);
            }
        }

        float m[2][4], lsum[2][4];
        f32x4 acc[2][4];
#pragma unroll
        for (int su = 0; su < 2; ++su)
#pragma unroll
            for (int rr = 0; rr < 4; ++rr) { m[su][rr] = -__builtin_inff(); lsum[su][rr] = 0.f; }
#pragma unroll
        for (int su = 0; su < 2; ++su)
#pragma unroll
            for (int hs = 0; hs < 4; ++hs) acc[su][hs] = (f32x4){0.f, 0.f, 0.f, 0.f};

        for (int e = 0; e < run; ++e) {
            const int kt = kt0 + e;
            const size_t kb = ((size_t)(b * T_ + kt * 64)) * 64;
            f32x4 sc[2][4];
            __builtin_amdgcn_s_setprio(1);
#pragma unroll
            for (int ks = 0; ks < 4; ++ks) {
                f32x4 a0 = (f32x4){0.f, 0.f, 0.f, 0.f};
                f32x4 a1 = (f32x4){0.f, 0.f, 0.f, 0.f};
#pragma unroll
                for (int cc = 0; cc < 2; ++cc) {
                    const size_t ko = kb + ((size_t)(ks * 16 + l16)) * 64 + cc * 32 + 8 * g;
                    short8 bh = *(const short8*)(Khi + ko);
                    short8 bl = *(const short8*)(Klo + ko);
                    a0 = __builtin_amdgcn_mfma_f32_16x16x32_bf16(aQh[0][cc], bh, a0, 0, 0, 0);
                    a0 = __builtin_amdgcn_mfma_f32_16x16x32_bf16(aQh[0][cc], bl, a0, 0, 0, 0);
                    a0 = __builtin_amdgcn_mfma_f32_16x16x32_bf16(aQl[0][cc], bh, a0, 0, 0, 0);
                    a1 = __builtin_amdgcn_mfma_f32_16x16x32_bf16(aQh[1][cc], bh, a1, 0, 0, 0);
                    a1 = __builtin_amdgcn_mfma_f32_16x16x32_bf16(aQh[1][cc], bl, a1, 0, 0, 0);
                    a1 = __builtin_amdgcn_mfma_f32_16x16x32_bf16(aQl[1][cc], bh, a1, 0, 0, 0);
                }
                sc[0][ks] = a0; sc[1][ks] = a1;
            }
            __builtin_amdgcn_s_setprio(0);
            if (kt == nkt - 1) {
#pragma unroll
                for (int su = 0; su < 2; ++su)
#pragma unroll
                    for (int ks = 0; ks < 4; ++ks)
#pragma unroll
                        for (int rr = 0; rr < 4; ++rr) {
                            int key = kt * 64 + ks * 16 + l16;
                            int row = q0 + su * 16 + 4 * g + rr;
                            if (key > row) sc[su][ks][rr] = -__builtin_inff();
                        }
            }
            float alv[2][4];
#pragma unroll
            for (int su = 0; su < 2; ++su) {
#pragma unroll
                for (int rr = 0; rr < 4; ++rr) {
                    float mt = fmaxf(fmaxf(sc[su][0][rr], sc[su][1][rr]),
                                     fmaxf(sc[su][2][rr], sc[su][3][rr]));
#pragma unroll
                    for (int msk = 1; msk < 16; msk <<= 1) mt = fmaxf(mt, __shfl_xor(mt, msk));
                    float mn = fmaxf(m[su][rr], mt);
                    alv[su][rr] = exp2f(m[su][rr] - mn);
                    m[su][rr] = mn;
                }
                float rs[4] = {0.f, 0.f, 0.f, 0.f};
#pragma unroll
                for (int ks = 0; ks < 4; ++ks)
#pragma unroll
                    for (int rr = 0; rr < 4; ++rr) {
                        float pv = exp2f(sc[su][ks][rr] - m[su][rr]);
                        rs[rr] += pv;
                        Pb[wv][su][4 * g + rr][ks * 16 + l16] = bf16_of(pv);
                    }
#pragma unroll
                for (int rr = 0; rr < 4; ++rr) {
#pragma unroll
                    for (int msk = 1; msk < 16; msk <<= 1) rs[rr] += __shfl_xor(rs[rr], msk);
                    lsum[su][rr] = lsum[su][rr] * alv[su][rr] + rs[rr];
                }
#pragma unroll
                for (int hs = 0; hs < 4; ++hs)
#pragma unroll
                    for (int rr = 0; rr < 4; ++rr) acc[su][hs][rr] *= alv[su][rr];
            }
            __builtin_amdgcn_s_setprio(1);
#pragma unroll
            for (int cc = 0; cc < 2; ++cc) {
                short8 ap0 = *(const short8*)&Pb[wv][0][l16][cc * 32 + 8 * g];
                short8 ap1 = *(const short8*)&Pb[wv][1][l16][cc * 32 + 8 * g];
#pragma unroll
                for (int hs = 0; hs < 4; ++hs) {
                    short8 bv = *(const short8*)(Vt + ((size_t)(b * 64 + hs * 16 + l16)) * T_
                                                 + kt * 64 + cc * 32 + 8 * g);
                    acc[0][hs] = __builtin_amdgcn_mfma_f32_16x16x32_bf16(ap0, bv, acc[0][hs], 0, 0, 0);
                    acc[1][hs] = __builtin_amdgcn_mfma_f32_16x16x32_bf16(ap1, bv, acc[1][hs], 0, 0, 0);
                }
            }
            __builtin_amdgcn_s_setprio(0);
        }

        // ---- flush partial (m,l fp32; acc bf16) ----
        {
            const int mh = i >> 1;
            const int Si = (i & 1) ? (mh + 1) * (mh + 1) : mh * (mh + 1);
            const int A = b * UPB + Si;
            const int Wf = (S * A + S - 1) / 65;
            const int slot = W - Wf;
            const int Tid = b * 128 + i;
            ushort_t* pa = PACC + ((size_t)(Tid * SLOTS + slot)) * 2048;
            float* pm = PML + ((size_t)(Tid * SLOTS + slot)) * 64;
#pragma unroll
            for (int su = 0; su < 2; ++su)
#pragma unroll
                for (int hs = 0; hs < 4; ++hs)
#pragma unroll
                    for (int rr = 0; rr < 4; ++rr)
                        pa[(su * 16 + 4 * g + rr) * 64 + hs * 16 + l16] = bf16_of(acc[su][hs][rr]);
            if (l16 == 0) {
#pragma unroll
                for (int su = 0; su < 2; ++su)
#pragma unroll
                    for (int rr = 0; rr < 4; ++rr) {
                        const int row = su * 16 + 4 * g + rr;
                        pm[row * 2] = m[su][rr];
                        pm[row * 2 + 1] = lsum[su][rr];
                    }
            }
        }
        u += run;
    }
}

// ---------------------------------------------------------------------------
// Kernel 3: merge partials per q-tile, normalize, write fp32 out.
// grid = 512 (one block per q-tile), 256 threads.
// ---------------------------------------------------------------------------
__global__ __launch_bounds__(256) void merge_k(
    const ushort_t* __restrict__ PACC, const float* __restrict__ PML,
    float* __restrict__ out, const int S, const int SLOTS)
{
    const int tid = threadIdx.x;
    const int Tid = blockIdx.x;
    const int b = Tid >> 7, i = Tid & 127;
    const int nkt = (i >> 1) + 1;
    const int mh = i >> 1;
    const int Si = (i & 1) ? (mh + 1) * (mh + 1) : mh * (mh + 1);
    const int A = b * UPB + Si;
    const int Wf = (S * A + S - 1) / 65;
    const int Wl = (S * (A + nkt - 1) + S - 1) / 65;
    const int n = Wl - Wf + 1;
    const int row = tid >> 3;
    const int c0 = (tid & 7) * 8;

    float mm = -__builtin_inff(), ll = 0.f;
    float ac[8];
#pragma unroll
    for (int k2 = 0; k2 < 8; ++k2) ac[k2] = 0.f;

    for (int p = 0; p < n; ++p) {
        const float* pm = PML + ((size_t)(Tid * SLOTS + p)) * 64 + row * 2;
        float m1 = pm[0], l1 = pm[1];
        short8 pv = *(const short8*)(PACC + ((size_t)(Tid * SLOTS + p)) * 2048 + row * 64 + c0);
        float mf = fmaxf(mm, m1);
        float a0 = exp2f(mm - mf), a1 = exp2f(m1 - mf);
        ll = ll * a0 + l1 * a1;
#pragma unroll
        for (int k2 = 0; k2 < 8; ++k2)
            ac[k2] = ac[k2] * a0 + f_of_bf16((ushort_t)pv[k2]) * a1;
        mm = mf;
    }
    float inv = 1.f / ll;
    float* op = out + ((size_t)(b * T_ + i * 32 + row)) * 64 + c0;
    float4 o0, o1;
    o0.x = ac[0] * inv; o0.y = ac[1] * inv; o0.z = ac[2] * inv; o0.w = ac[3] * inv;
    o1.x = ac[4] * inv; o1.y = ac[5] * inv; o1.z = ac[6] * inv; o1.w = ac[7] * inv;
    *(float4*)op = o0;
    *(float4*)(op + 4) = o1;
}

// ---------------------------------------------------------------------------
// Fallback kernel (round-2 flash, proven, 10 MB ws): used only if ws_size
// is too small for stream-K partials.
// ---------------------------------------------------------------------------
__global__ __launch_bounds__(256, 2) void flash_attn(
    const ushort_t* __restrict__ Qhi, const ushort_t* __restrict__ Qlo,
    const ushort_t* __restrict__ Khi, const ushort_t* __restrict__ Klo,
    const ushort_t* __restrict__ Vt, float* __restrict__ out)
{
    __shared__ __align__(16) ushort_t Pb[4][2][16][72];
    __shared__ float mrg[2][64][3][26];

    const int tid = threadIdx.x;
    const int p = tid >> 6;
    const int lane = tid & 63;
    const int l16 = lane & 15, g = lane >> 4;

    const int bid = blockIdx.x;
    const int xg = bid & 7;
    const int b = xg & 3;
    const int jj = bid >> 3;
    const int i = (xg >> 2) ? (126 - 2 * jj) : (127 - 2 * jj);
    const int q0 = i * 32;
    const int nkt = (q0 + 32 + 63) >> 6;

    short8 aQh[2][2], aQl[2][2];
#pragma unroll
    for (int su = 0; su < 2; ++su) {
        const size_t qb = ((size_t)(b * T_ + q0 + su * 16 + l16)) * 64;
#pragma unroll
        for (int cc = 0; cc < 2; ++cc) {
            aQh[su][cc] = *(const short8*)(Qhi + qb + cc * 32 + 8 * g);
            aQl[su][cc] = *(const short8*)(Qlo + qb + cc * 32 + 8 * g);
        }
    }

    float m[2][4], lsum[2][4];
    f32x4 acc[2][4];
#pragma unroll
    for (int su = 0; su < 2; ++su)
#pragma unroll
        for (int rr = 0; rr < 4; ++rr) { m[su][rr] = -__builtin_inff(); lsum[su][rr] = 0.f; }
#pragma unroll
    for (int su = 0; su < 2; ++su)
#pragma unroll
        for (int hs = 0; hs < 4; ++hs) acc[su][hs] = (f32x4){0.f, 0.f, 0.f, 0.f};

    for (int kt = p; kt < nkt; kt += 4) {
        const size_t kb = ((size_t)(b * T_ + kt * 64)) * 64;
        f32x4 sc[2][4];
        __builtin_amdgcn_s_setprio(1);
#pragma unroll
        for (int ks = 0; ks < 4; ++ks) {
            f32x4 a0 = (f32x4){0.f, 0.f, 0.f, 0.f};
            f32x4 a1 = (f32x4){0.f, 0.f, 0.f, 0.f};
#pragma unroll
            for (int cc = 0; cc < 2; ++cc) {
                const size_t ko = kb + ((size_t)(ks * 16 + l16)) * 64 + cc * 32 + 8 * g;
                short8 bh = *(const short8*)(Khi + ko);
                short8 bl = *(const short8*)(Klo + ko);
                a0 = __builtin_amdgcn_mfma_f32_16x16x32_bf16(aQh[0][cc], bh, a0, 0, 0, 0);
                a0 = __builtin_amdgcn_mfma_f32_16x16x32_bf16(aQh[0][cc], bl, a0, 0, 0, 0);
                a0 = __builtin_amdgcn_mfma_f32_16x16x32_bf16(aQl[0][cc], bh, a0, 0, 0, 0);
                a1 = __builtin_amdgcn_mfma_f32_16x16x32_bf16(aQh[1][cc], bh, a1, 0, 0, 0);
                a1 = __builtin_amdgcn_mfma_f32_16x16x32_bf16(aQh[1][cc], bl, a1, 0, 0, 0);
                a1 = __builtin_amdgcn_mfma_f32_16x16x32_bf16(aQl[1][cc], bh, a1, 0, 0, 0);
            }
            sc[0][ks] = a0; sc[1][ks] = a1;
        }
        __builtin_amdgcn_s_setprio(0);
        if (kt == nkt - 1) {
#pragma unroll
            for (int su = 0; su < 2; ++su)
#pragma unroll
                for (int ks = 0; ks < 4; ++ks)
#pragma unroll
                    for (int rr = 0; rr < 4; ++rr) {
                        int key = kt * 64 + ks * 16 + l16;
                        int row = q0 + su * 16 + 4 * g + rr;
                        if (key > row) sc[su][ks][rr] = -__builtin_inff();
                    }
        }
        float alv[2][4];
#pragma unroll
        for (int su = 0; su < 2; ++su) {
#pragma unroll
            for (int rr = 0; rr < 4; ++rr) {
                float mt = fmaxf(fmaxf(sc[su][0][rr], sc[su][1][rr]),
                                 fmaxf(sc[su][2][rr], sc[su][3][rr]));
#pragma unroll
                for (int msk = 1; msk < 16; msk <<= 1) mt = fmaxf(mt, __shfl_xor(mt, msk));
                float mn = fmaxf(m[su][rr], mt);
                alv[su][rr] = exp2f(m[su][rr] - mn);
                m[su][rr] = mn;
            }
            float rs[4] = {0.f, 0.f, 0.f, 0.f};
#pragma unroll
            for (int ks = 0; ks < 4; ++ks)
#pragma unroll
                for (int rr = 0; rr < 4; ++rr) {
                    float pv = exp2f(sc[su][ks][rr] - m[su][rr]);
                    rs[rr] += pv;
                    Pb[p][su][4 * g + rr][ks * 16 + l16] = bf16_of(pv);
                }
#pragma unroll
            for (int rr = 0; rr < 4; ++rr) {
#pragma unroll
                for (int msk = 1; msk < 16; msk <<= 1) rs[rr] += __shfl_xor(rs[rr], msk);
                lsum[su][rr] = lsum[su][rr] * alv[su][rr] + rs[rr];
            }
#pragma unroll
            for (int hs = 0; hs < 4; ++hs)
#pragma unroll
                for (int rr = 0; rr < 4; ++rr) acc[su][hs][rr] *= alv[su][rr];
        }
        __builtin_amdgcn_s_setprio(1);
#pragma unroll
        for (int cc = 0; cc < 2; ++cc) {
            short8 ap0 = *(const short8*)&Pb[p][0][l16][cc * 32 + 8 * g];
            short8 ap1 = *(const short8*)&Pb[p][1][l16][cc * 32 + 8 * g];
#pragma unroll
            for (int hs = 0; hs < 4; ++hs) {
                short8 bv = *(const short8*)(Vt + ((size_t)(b * 64 + hs * 16 + l16)) * T_
                                             + kt * 64 + cc * 32 + 8 * g);
                acc[0][hs] = __builtin_amdgcn_mfma_f32_16x16x32_bf16(ap0, bv, acc[0][hs], 0, 0, 0);
                acc[1][hs] = __builtin_amdgcn_mfma_f32_16x16x32_bf16(ap1, bv, acc[1][hs], 0, 0, 0);
            }
        }
        __builtin_amdgcn_s_setprio(0);
    }

    if (p > 0) {
#pragma unroll
        for (int su = 0; su < 2; ++su) {
            float* mp = &mrg[su][lane][p - 1][0];
#pragma unroll
            for (int rr = 0; rr < 4; ++rr) { mp[rr] = m[su][rr]; mp[4 + rr] = lsum[su][rr]; }
#pragma unroll
            for (int hs = 0; hs < 4; ++hs)
#pragma unroll
                for (int rr = 0; rr < 4; ++rr) mp[8 + hs * 4 + rr] = acc[su][hs][rr];
        }
    }
    __syncthreads();
    if (p == 0) {
#pragma unroll
        for (int su = 0; su < 2; ++su) {
#pragma unroll
            for (int rr = 0; rr < 4; ++rr) {
                float mm = m[su][rr], ll = lsum[su][rr];
                float ac[4];
#pragma unroll
                for (int hs = 0; hs < 4; ++hs) ac[hs] = acc[su][hs][rr];
#pragma unroll
                for (int pp = 0; pp < 3; ++pp) {
                    const float* mp = &mrg[su][lane][pp][0];
                    float m1 = mp[rr], l1 = mp[4 + rr];
                    float mf = fmaxf(mm, m1);
                    float a0 = exp2f(mm - mf);
                    float a1 = exp2f(m1 - mf);
                    ll = ll * a0 + l1 * a1;
#pragma unroll
                    for (int hs = 0; hs < 4; ++hs)
                        ac[hs] = ac[hs] * a0 + mp[8 + hs * 4 + rr] * a1;
                    mm = mf;
                }
                float inv = 1.f / ll;
                const size_t ob = ((size_t)(b * T_ + q0 + su * 16 + 4 * g + rr)) * 64;
#pragma unroll
                for (int hs = 0; hs < 4; ++hs) out[ob + hs * 16 + l16] = ac[hs] * inv;
            }
        }
    }
}

// ---------------------------------------------------------------------------
extern "C" void kernel_launch(void* const* d_in, const int* in_sizes, int n_in,
                              void* d_out, int out_size, void* d_ws, size_t ws_size,
                              hipStream_t stream) {
    const float* x  = (const float*)d_in[0];
    const float* Wq = (const float*)d_in[1];
    const float* Wk = (const float*)d_in[2];
    const float* Wv = (const float*)d_in[3];
    float* out = (float*)d_out;

    const size_t N = (size_t)B_ * T_ * 64;
    ushort_t* Qhi = (ushort_t*)d_ws;
    ushort_t* Qlo = Qhi + N;
    ushort_t* Khi = Qlo + N;
    ushort_t* Klo = Khi + N;
    ushort_t* Vt  = Klo + N;
    ushort_t* PACC = Vt + N;

    const size_t base = 5 * N * sizeof(ushort_t);                       // 10.5 MB
    const size_t need12 = base + (size_t)512 * 13 * (2048 * 2 + 256);   // ~39.5 MB
    const size_t need8  = base + (size_t)512 * 9  * (2048 * 2 + 256);   // ~30.6 MB

    qkv_proj<<<512, 256, 0, stream>>>(x, Wq, Wk, Wv, Qhi, Qlo, Khi, Klo, Vt);

    if (ws_size >= need12) {
        const int S = 12, SLOTS = 13;                 // 3072 waves, 768 blocks
        float* PML = (float*)(PACC + (size_t)512 * SLOTS * 2048);
        flash_sk<<<768, 256, 0, stream>>>(Qhi, Qlo, Khi, Klo, Vt, PACC, PML, S, SLOTS);
        merge_k<<<512, 256, 0, stream>>>(PACC, PML, out, S, SLOTS);
    } else if (ws_size >= need8) {
        const int S = 8, SLOTS = 9;                   // 2048 waves, 512 blocks
        float* PML = (float*)(PACC + (size_t)512 * SLOTS * 2048);
        flash_sk<<<512, 256, 0, stream>>>(Qhi, Qlo, Khi, Klo, Vt, PACC, PML, S, SLOTS);
        merge_k<<<512, 256, 0, stream>>>(PACC, PML, out, S, SLOTS);
    } else {
        flash_attn<<<512, 256, 0, stream>>>(Qhi, Qlo, Khi, Klo, Vt, out);
    }
}